// Round 5
// baseline (1315.736 us; speedup 1.0000x reference)
//
#include <hip/hip_runtime.h>
#include <stdint.h>

#define ROWS   16384   // B*S
#define KDIM   256
#define DMDIM  512
#define DOUTD  1024
#define BANKN  4096
#define DIND   1024
#define HDIMD  2048
#define FPAD   1024    // max fixup rows

typedef unsigned int u32;
typedef unsigned long long u64;
typedef _Float16 v8h __attribute__((ext_vector_type(8)));
typedef short    v8s __attribute__((ext_vector_type(8)));
typedef float    v4f __attribute__((ext_vector_type(4)));

// ---------- split: v = main(f16) + res(f16)/2048 ; res stored pre-scaled by 2048 ----------
__device__ __forceinline__ void pack8(const float* f, uint4& mc, uint4& rc) {
    v8h m, r;
    #pragma unroll
    for (int j = 0; j < 8; j++) {
        _Float16 h = (_Float16)f[j];
        m[j] = h;
        r[j] = (_Float16)((f[j] - (float)h) * 2048.0f);
    }
    mc = __builtin_bit_cast(uint4, m);
    rc = __builtin_bit_cast(uint4, r);
}
__device__ __forceinline__ u32 pack_split(float v) {
    _Float16 h = (_Float16)v;
    _Float16 l = (_Float16)((v - (float)h) * 2048.0f);
    return (u32)__builtin_bit_cast(unsigned short, h) |
           ((u32)__builtin_bit_cast(unsigned short, l) << 16);
}
__device__ __forceinline__ v4f mfma16(v8h a, v8h b, v4f c) {
    return __builtin_amdgcn_mfma_f32_16x16x32_f16(a, b, c, 0, 0, 0);
}
__device__ __forceinline__ void gl_lds16(const u32* g, u32* l) {
    __builtin_amdgcn_global_load_lds(g, l, 16, 0, 0);
}

// ================= split-f16 MFMA GEMM, octet-planar format =================
// A:[M x K], Bt:[N x K], packed octet-planar: per row, K/8 octets, each octet =
// 16B main(8 f16) + 16B res(8 f16).  C = A*Bt^T via 3-pass split.
// OM=0: fp32 partials at Cv + bz*M*N (no bias).
// OM=1: relu(v+bias) packed -> OCTET-PLANAR output [M x N] (direct, no reorder).
template<int OM>
__global__ __launch_bounds__(256, 3)
void gemm_mfma(const uint4* __restrict__ A, const uint4* __restrict__ Bt,
               const float* __restrict__ bias, void* __restrict__ Cv,
               int K, int kLen)
{
    __shared__ u32 S[8448];          // staging: As=S[0:4096], Bs=S[4096:8192]; epilogue: 64x132
    u32* As = S;
    u32* Bs = S + 4096;
    const int N = gridDim.x * 128;
    const int M = gridDim.y * 128;

    // XCD-aware remap (all grids used are multiples of 8 blocks)
    long gx = gridDim.x, gy = gridDim.y, gz = gridDim.z;
    long flat = ((long)blockIdx.z * gy + blockIdx.y) * gx + blockIdx.x;
    long nb = gx * gy * gz;
    long lid = (flat & 7) * (nb >> 3) + (flat >> 3);
    int bx = (int)(lid % gx);
    long t2 = lid / gx;
    int by = (int)(t2 % gy);
    int bz = (int)(t2 / gy);

    const int m0 = by * 128, n0 = bx * 128;
    const int kStart = bz * kLen;

    const int tid = threadIdx.x;
    const int lane = tid & 63, wv = tid >> 6;
    const int lx = lane & 15, q = lane >> 4;
    const int wm = (wv >> 1) * 64, wn = (wv & 1) * 64;

    // staging: instr r covers chunks c = r*256 + tid; LDS pos p=tid&7 holds
    // global (plane,sub) = decode(p ^ (row&7))
    const int srow = tid >> 3;                 // + r*32
    const int spq  = (tid & 7) ^ (srow & 7);
    const int spl  = spq >> 2, ssub = spq & 3;
    const int K4 = K >> 2;                     // 16B chunks per row
    const uint4* gA = A + (size_t)(m0 + srow) * K4 + (kStart >> 2) + ssub * 2 + spl;
    const uint4* gB = Bt + (size_t)(n0 + srow) * K4 + (kStart >> 2) + ssub * 2 + spl;

    // fragment LDS chunk offsets: row m, main: m*8 + (q ^ (m&7)); res: m*8 + ((4+q)^(m&7))
    int amO[4], arO[4], bmO[4], brO[4];
    #pragma unroll
    for (int i = 0; i < 4; i++) {
        int m = wm + i * 16 + lx;
        amO[i] = m * 8 + (q ^ (m & 7));
        arO[i] = m * 8 + ((4 + q) ^ (m & 7));
        int n = wn + i * 16 + lx;
        bmO[i] = n * 8 + (q ^ (n & 7));
        brO[i] = n * 8 + ((4 + q) ^ (n & 7));
    }

    v4f acc1[4][4], acc2[4][4];
    #pragma unroll
    for (int i = 0; i < 4; i++)
        #pragma unroll
        for (int j = 0; j < 4; j++) { v4f z = {0.f,0.f,0.f,0.f}; acc1[i][j] = z; acc2[i][j] = z; }

    for (int kt = 0; kt < kLen; kt += 32) {
        #pragma unroll
        for (int r = 0; r < 4; r++) {
            gl_lds16((const u32*)(gA + (size_t)r * 32 * K4), As + (r * 256 + wv * 64) * 4);
            gl_lds16((const u32*)(gB + (size_t)r * 32 * K4), Bs + (r * 256 + wv * 64) * 4);
        }
        gA += 8; gB += 8;   // advance 32 k = 8 chunks
        __syncthreads();

        v8h am[4], ar[4], bm[4], br[4];
        #pragma unroll
        for (int i = 0; i < 4; i++) {
            am[i] = __builtin_bit_cast(v8h, *(const uint4*)(As + amO[i] * 4));
            ar[i] = __builtin_bit_cast(v8h, *(const uint4*)(As + arO[i] * 4));
            bm[i] = __builtin_bit_cast(v8h, *(const uint4*)(Bs + bmO[i] * 4));
            br[i] = __builtin_bit_cast(v8h, *(const uint4*)(Bs + brO[i] * 4));
        }
        #pragma unroll
        for (int mi = 0; mi < 4; mi++)
            #pragma unroll
            for (int ni = 0; ni < 4; ni++) {
                acc1[mi][ni] = mfma16(am[mi], bm[ni], acc1[mi][ni]);
                acc2[mi][ni] = mfma16(am[mi], br[ni], acc2[mi][ni]);
                acc2[mi][ni] = mfma16(ar[mi], bm[ni], acc2[mi][ni]);
            }
        __syncthreads();
    }

    const float RS = 1.0f / 2048.0f;
    if (OM == 0) {
        #pragma unroll
        for (int mi = 0; mi < 4; mi++)
            #pragma unroll
            for (int ni = 0; ni < 4; ni++) {
                int col = n0 + wn + ni * 16 + lx;
                #pragma unroll
                for (int r = 0; r < 4; r++) {
                    int row = m0 + wm + mi * 16 + q * 4 + r;
                    ((float*)Cv)[(size_t)bz * M * N + (size_t)row * N + col] =
                        acc1[mi][ni][r] + acc2[mi][ni][r] * RS;
                }
            }
    } else {
        // direct octet-planar epilogue: two 64x128 halves through LDS (stride 132, 2-way banked)
        #pragma unroll
        for (int h = 0; h < 2; h++) {
            __syncthreads();
            if ((wv >> 1) == h) {
                #pragma unroll
                for (int mi = 0; mi < 4; mi++)
                    #pragma unroll
                    for (int ni = 0; ni < 4; ni++) {
                        int lc = wn + ni * 16 + lx;
                        float bi = bias[n0 + lc];
                        #pragma unroll
                        for (int r = 0; r < 4; r++) {
                            int lr = mi * 16 + q * 4 + r;
                            float v = fmaxf(acc1[mi][ni][r] + acc2[mi][ni][r] * RS + bi, 0.f);
                            S[lr * 132 + lc] = pack_split(v);
                        }
                    }
            }
            __syncthreads();
            int lr = tid >> 2;                 // 0..63
            int og = (tid & 3) * 4;            // octets og..og+3 (block-local)
            size_t grow = (size_t)(m0 + h * 64 + lr) * (N >> 2);
            #pragma unroll
            for (int oo = 0; oo < 4; oo++) {
                int o = og + oo;
                u32 c[8];
                #pragma unroll
                for (int j = 0; j < 8; j++) c[j] = S[lr * 132 + o * 8 + j];
                uint4 mc, rc;
                mc.x = (c[0] & 0xffffu) | (c[1] << 16);
                mc.y = (c[2] & 0xffffu) | (c[3] << 16);
                mc.z = (c[4] & 0xffffu) | (c[5] << 16);
                mc.w = (c[6] & 0xffffu) | (c[7] << 16);
                rc.x = (c[0] >> 16) | (c[1] & 0xffff0000u);
                rc.y = (c[2] >> 16) | (c[3] & 0xffff0000u);
                rc.z = (c[4] >> 16) | (c[5] & 0xffff0000u);
                rc.w = (c[6] >> 16) | (c[7] & 0xffff0000u);
                // BUGFIX R4: global chunk must include the column-block offset n0/4
                ((uint4*)Cv)[grow + (n0 >> 2) + o * 2]     = mc;
                ((uint4*)Cv)[grow + (n0 >> 2) + o * 2 + 1] = rc;
            }
        }
    }
}

// ---------------- row-major split-pack ----------------
__global__ __launch_bounds__(256)
void packrows_k(const float* __restrict__ s, uint4* __restrict__ d, long nOct)
{
    long i = (long)blockIdx.x * 256 + threadIdx.x;
    if (i >= nOct) return;
    float f[8];
    float4 a = ((const float4*)s)[i * 2], b = ((const float4*)s)[i * 2 + 1];
    f[0]=a.x; f[1]=a.y; f[2]=a.z; f[3]=a.w; f[4]=b.x; f[5]=b.y; f[6]=b.z; f[7]=b.w;
    uint4 mc, rc; pack8(f, mc, rc);
    d[i * 2] = mc; d[i * 2 + 1] = rc;
}

// ---------------- transpose + split-pack: W[K x N] f32 -> octet-planar [N x K] ----------------
__global__ __launch_bounds__(256)
void tsplit_k(const float* __restrict__ W, uint4* __restrict__ Wt, int K, int N)
{
    __shared__ float L[32][33];
    int k0 = blockIdx.y * 32, n0 = blockIdx.x * 32;
    int r = threadIdx.x >> 3, c4 = (threadIdx.x & 7) * 4;
    float4 v = *(const float4*)(W + (size_t)(k0 + r) * N + n0 + c4);
    L[r][c4 + 0] = v.x; L[r][c4 + 1] = v.y; L[r][c4 + 2] = v.z; L[r][c4 + 3] = v.w;
    __syncthreads();
    if (threadIdx.x < 128) {
        int n = threadIdx.x >> 2, oct = threadIdx.x & 3;
        float f[8];
        #pragma unroll
        for (int j = 0; j < 8; j++) f[j] = L[oct * 8 + j][n];
        uint4 mc, rc; pack8(f, mc, rc);
        size_t base = (size_t)(n0 + n) * (K >> 2) + (size_t)((k0 >> 3) + oct) * 2;
        Wt[base] = mc; Wt[base + 1] = rc;
    }
}

// ---------------- 1/max(||bank_keys[n]||,1e-12) ----------------
__global__ __launch_bounds__(64)
void invkn_k(const float* __restrict__ keys, float* __restrict__ inv_kn)
{
    int n = blockIdx.x, l = threadIdx.x;
    const float4* r = (const float4*)(keys + (size_t)n * 512);
    float4 a = r[l], b = r[l + 64];
    float s = a.x*a.x + a.y*a.y + a.z*a.z + a.w*a.w
            + b.x*b.x + b.y*b.y + b.z*b.z + b.w*b.w;
    #pragma unroll
    for (int off = 32; off; off >>= 1) s += __shfl_xor(s, off);
    if (l == 0) inv_kn[n] = 1.0f / fmaxf(sqrtf(s), 1e-12f);
}

// ---------------- masked scaled softmax, writes packed attn directly ----------------
__global__ __launch_bounds__(256)
void softmax_k(const float* __restrict__ Mw, const float* __restrict__ inv_kn,
               const float* __restrict__ used, const float* __restrict__ sc,
               uint4* __restrict__ pattn)
{
    const int k = blockIdx.x, tid = threadIdx.x;
    __shared__ float red[256];
    float m0 = Mw[(size_t)k*512 + tid];
    float m1 = Mw[(size_t)k*512 + 256 + tid];
    red[tid] = m0*m0 + m1*m1;
    __syncthreads();
    for (int s = 128; s > 0; s >>= 1) { if (tid < s) red[tid] += red[tid+s]; __syncthreads(); }
    float scale = 4.0f / fmaxf(sqrtf(red[0]), 1e-12f);
    __syncthreads();
    float vals[16];
    float mx = -3.0e38f;
    #pragma unroll
    for (int j = 0; j < 16; j++) {
        int n = tid * 16 + j;
        float v = sc[(size_t)k*4096 + n] * scale * inv_kn[n];
        v = (used[n] > 0.5f) ? v : -1e30f;
        vals[j] = v; mx = fmaxf(mx, v);
    }
    red[tid] = mx; __syncthreads();
    for (int s = 128; s > 0; s >>= 1) { if (tid < s) red[tid] = fmaxf(red[tid], red[tid+s]); __syncthreads(); }
    mx = red[0]; __syncthreads();
    float sum = 0.f;
    #pragma unroll
    for (int j = 0; j < 16; j++) { float e = expf(vals[j] - mx); vals[j] = e; sum += e; }
    red[tid] = sum; __syncthreads();
    for (int s = 128; s > 0; s >>= 1) { if (tid < s) red[tid] += red[tid+s]; __syncthreads(); }
    float inv = 1.0f / red[0];
    #pragma unroll
    for (int j = 0; j < 16; j++) vals[j] *= inv;
    uint4 mc0, rc0, mc1, rc1;
    pack8(vals, mc0, rc0);
    pack8(vals + 8, mc1, rc1);
    uint4* outp = pattn + (size_t)k * 1024 + tid * 4;
    outp[0] = mc0; outp[1] = rc0; outp[2] = mc1; outp[3] = rc1;
}

// ---------------- reduce 8 AV partials + RMS-norm + pack rn ----------------
__global__ __launch_bounds__(64)
void redk_rn_k(const float* __restrict__ partB, const float* __restrict__ Mw,
               const float* __restrict__ g, uint4* __restrict__ prn)
{
    int k = blockIdx.x, t = threadIdx.x;
    float r[8];
    {
        float4 a = *(const float4*)(Mw + (size_t)k*512 + t*8);
        float4 b = *(const float4*)(Mw + (size_t)k*512 + t*8 + 4);
        r[0]=a.x; r[1]=a.y; r[2]=a.z; r[3]=a.w; r[4]=b.x; r[5]=b.y; r[6]=b.z; r[7]=b.w;
    }
    #pragma unroll
    for (int z = 0; z < 8; z++) {
        const float* p = partB + (size_t)z * 131072 + (size_t)k * 512 + t * 8;
        float4 a = *(const float4*)p, b = *(const float4*)(p + 4);
        r[0]+=a.x; r[1]+=a.y; r[2]+=a.z; r[3]+=a.w; r[4]+=b.x; r[5]+=b.y; r[6]+=b.z; r[7]+=b.w;
    }
    float ss = 0.f;
    #pragma unroll
    for (int j = 0; j < 8; j++) ss += r[j]*r[j];
    #pragma unroll
    for (int off = 32; off; off >>= 1) ss += __shfl_xor(ss, off);
    float inv = 1.0f / sqrtf(ss * (1.0f/512.0f) + 1e-6f);
    float4 ga = *(const float4*)(g + t*8), gb = *(const float4*)(g + t*8 + 4);
    float o[8] = { r[0]*ga.x*inv, r[1]*ga.y*inv, r[2]*ga.z*inv, r[3]*ga.w*inv,
                   r[4]*gb.x*inv, r[5]*gb.y*inv, r[6]*gb.z*inv, r[7]*gb.w*inv };
    uint4 mc, rc; pack8(o, mc, rc);
    prn[(size_t)k * 128 + t * 2] = mc;
    prn[(size_t)k * 128 + t * 2 + 1] = rc;
}

// ---------------- reduce 4 ytab partials + bias ----------------
__global__ __launch_bounds__(256)
void ytabred_k(const float* __restrict__ yp, const float* __restrict__ bias,
               float* __restrict__ ytab)
{
    int i = blockIdx.x * 256 + threadIdx.x;   // float4 idx, 65536 total
    const float4* p = (const float4*)yp;
    float4 s = p[i];
    #pragma unroll
    for (int z = 1; z < 4; z++) {
        float4 t = p[(size_t)z * 65536 + i];
        s.x += t.x; s.y += t.y; s.z += t.z; s.w += t.w;
    }
    float4 b = ((const float4*)bias)[i & 255];
    s.x += b.x; s.y += b.y; s.z += b.z; s.w += b.w;
    ((float4*)ytab)[i] = s;
}

// ---------------- fused: reduce GEMM2 partials + bias + argmax + masks + flags ----------------
__global__ __launch_bounds__(64)
void logits_flag_k(const float* __restrict__ p2, const float* __restrict__ bias,
                   u64* __restrict__ masks, int* __restrict__ cArr,
                   int* __restrict__ flags, int rowsC)
{
    int row = blockIdx.x, l = threadIdx.x;
    float v[4];
    #pragma unroll
    for (int j = 0; j < 4; j++) {
        int c = j * 64 + l;
        float s = bias[c];
        #pragma unroll
        for (int z = 0; z < 4; z++)
            s += p2[(size_t)z * rowsC * 256 + (size_t)row * 256 + c];
        v[j] = s;
    }
    float bv = v[0]; int bp = l;
    if (v[1] > bv) { bv = v[1]; bp = 64 + l; }
    if (v[2] > bv) { bv = v[2]; bp = 128 + l; }
    if (v[3] > bv) { bv = v[3]; bp = 192 + l; }
    #pragma unroll
    for (int off = 32; off; off >>= 1) {
        float ov = __shfl_xor(bv, off);
        int   op = __shfl_xor(bp, off);
        if (ov > bv || (ov == bv && op < bp)) { bv = ov; bp = op; }
    }
    u64 w[4];
    #pragma unroll
    for (int j = 0; j < 4; j++) {
        float t = v[j] + 0.1f;
        int idx = j * 64 + l;
        w[j] = __ballot((t > bv) || (t == bv && idx < bp));
    }
    const float D = 1e-3f;
    bool r = false;
    #pragma unroll
    for (int j = 0; j < 4; j++) {
        int idx = j * 64 + l;
        r |= (v[j] > bv - D) && (idx != bp);
        r |= fabsf(v[j] + 0.1f - bv) < D;
    }
    u64 any = __ballot(r);
    if (l == 0) {
        masks[(size_t)row*4+0]=w[0]; masks[(size_t)row*4+1]=w[1];
        masks[(size_t)row*4+2]=w[2]; masks[(size_t)row*4+3]=w[3];
        cArr[row] = bp;
        flags[row] = (any != 0ULL) ? 1 : 0;
    }
}

// ---------------- fp32 GEMM 64x64 (fixup path, exact) ----------------
template<bool RELU>
__global__ __launch_bounds__(256)
void gemm64(const float* __restrict__ A, const float* __restrict__ Bm,
            const float* __restrict__ bias, float* __restrict__ C,
            int N, int K, const int* __restrict__ mcount)
{
    if ((int)blockIdx.y * 64 >= *mcount) return;
    __shared__ float As[16][68];
    __shared__ float Bs[16][68];
    const int tid = threadIdx.x;
    const int tx = tid & 15, ty = tid >> 4;
    const int m0 = blockIdx.y * 64;
    const int n0 = blockIdx.x * 64;
    float acc[4][4];
    #pragma unroll
    for (int i = 0; i < 4; i++)
        #pragma unroll
        for (int j = 0; j < 4; j++) acc[i][j] = 0.f;

    for (int kt = 0; kt < K; kt += 16) {
        {
            int m = tid >> 2, kq = tid & 3;
            float4 av = *(const float4*)(A + (size_t)(m0 + m) * K + kt + kq * 4);
            As[kq*4+0][m]=av.x; As[kq*4+1][m]=av.y; As[kq*4+2][m]=av.z; As[kq*4+3][m]=av.w;
        }
        {
            int n4 = tid & 15, kk = tid >> 4;
            float4 bv = *(const float4*)(Bm + (size_t)(kt + kk) * N + n0 + n4 * 4);
            *(float4*)&Bs[kk][n4 * 4] = bv;
        }
        __syncthreads();
        #pragma unroll
        for (int k = 0; k < 16; k++) {
            float4 a0 = *(const float4*)&As[k][ty * 4];
            float4 b0 = *(const float4*)&Bs[k][tx * 4];
            float a[4] = {a0.x, a0.y, a0.z, a0.w};
            float b[4] = {b0.x, b0.y, b0.z, b0.w};
            #pragma unroll
            for (int i = 0; i < 4; i++)
                #pragma unroll
                for (int j = 0; j < 4; j++)
                    acc[i][j] = fmaf(a[i], b[j], acc[i][j]);
        }
        __syncthreads();
    }
    float4 bi = *(const float4*)(bias + n0 + tx * 4);
    #pragma unroll
    for (int i = 0; i < 4; i++) {
        int m = m0 + ty * 4 + i;
        float o0 = acc[i][0]+bi.x, o1 = acc[i][1]+bi.y, o2 = acc[i][2]+bi.z, o3 = acc[i][3]+bi.w;
        if (RELU) { o0=fmaxf(o0,0.f); o1=fmaxf(o1,0.f); o2=fmaxf(o2,0.f); o3=fmaxf(o3,0.f); }
        *(float4*)(C + (size_t)m * N + n0 + tx * 4) = make_float4(o0, o1, o2, o3);
    }
}

__global__ __launch_bounds__(256)
void compact_k(const int* __restrict__ flags, int* __restrict__ ridx, int* __restrict__ cnt)
{
    int row = blockIdx.x * 256 + threadIdx.x;
    if (row >= ROWS) return;
    if (flags[row]) {
        int p = atomicAdd(cnt, 1);
        if (p < FPAD) ridx[p] = row;
    }
}

__global__ __launch_bounds__(256)
void gatherx_k(const float* __restrict__ x, const int* __restrict__ ridx,
               const int* __restrict__ cnt, float* __restrict__ xg)
{
    int b = blockIdx.x;
    int n = *cnt; if (n > FPAD) n = FPAD;
    if (b >= n) return;
    int row = ridx[b];
    ((float4*)(xg + (size_t)b * 1024))[threadIdx.x] =
        ((const float4*)(x + (size_t)row * 1024))[threadIdx.x];
}

// ---------------- recompute masks/cArr for fixed rows from exact logits ----------------
__global__ __launch_bounds__(64)
void fixmask_k(const float* __restrict__ lgg, const int* __restrict__ ridx,
               const int* __restrict__ cnt, u64* __restrict__ masks, int* __restrict__ cArr)
{
    int b = blockIdx.x;
    int n = *cnt; if (n > FPAD) n = FPAD;
    if (b >= n) return;
    int row = ridx[b], l = threadIdx.x;
    const float* lg = lgg + (size_t)b * 256;
    float v[4] = { lg[l], lg[64 + l], lg[128 + l], lg[192 + l] };
    float bv = v[0]; int bp = l;
    if (v[1] > bv) { bv = v[1]; bp = 64 + l; }
    if (v[2] > bv) { bv = v[2]; bp = 128 + l; }
    if (v[3] > bv) { bv = v[3]; bp = 192 + l; }
    #pragma unroll
    for (int off = 32; off; off >>= 1) {
        float ov = __shfl_xor(bv, off);
        int   op = __shfl_xor(bp, off);
        if (ov > bv || (ov == bv && op < bp)) { bv = ov; bp = op; }
    }
    u64 w[4];
    #pragma unroll
    for (int j = 0; j < 4; j++) {
        float t = v[j] + 0.1f;
        int idx = j * 64 + l;
        w[j] = __ballot((t > bv) || (t == bv && idx < bp));
    }
    if (l == 0) {
        masks[(size_t)row*4+0]=w[0]; masks[(size_t)row*4+1]=w[1];
        masks[(size_t)row*4+2]=w[2]; masks[(size_t)row*4+3]=w[3];
        cArr[row] = bp;
    }
}

// ---------------- sequential scan: 8 chains, register-resident via readlane ----------------
__global__ __launch_bounds__(64)
void scan2_k(const u64* __restrict__ masks, const int* __restrict__ cArr,
             const float* __restrict__ prev_mode, int* __restrict__ midx)
{
    int b = blockIdx.x, l = threadIdx.x;
    float4 pm = ((const float4*)(prev_mode + (size_t)b * 256))[l];
    int my = -1;
    if (pm.x > 0.5f) my = l * 4 + 0;
    if (pm.y > 0.5f) my = l * 4 + 1;
    if (pm.z > 0.5f) my = l * 4 + 2;
    if (pm.w > 0.5f) my = l * 4 + 3;
    u64 bal = __ballot(my >= 0);
    int prev = 0;
    if (bal) {
        int src = __ffsll(bal) - 1;
        prev = __builtin_amdgcn_readlane(my, src);
    }
    const int base = b * 2048;
    ulonglong2 nx01 = *(const ulonglong2*)(masks + (size_t)(base + l) * 4);
    ulonglong2 nx23 = *(const ulonglong2*)(masks + (size_t)(base + l) * 4 + 2);
    int nxc = cArr[base + l];
    for (int seg = 0; seg < 32; ++seg) {
        ulonglong2 c01 = nx01, c23 = nx23;
        int cc = nxc;
        if (seg < 31) {
            int row = base + (seg + 1) * 64 + l;
            nx01 = *(const ulonglong2*)(masks + (size_t)row * 4);
            nx23 = *(const ulonglong2*)(masks + (size_t)row * 4 + 2);
            nxc = cArr[row];
        }
        int myres = 0;
        for (int j = 0; j < 64; ++j) {
            u64 wlo = (prev & 64) ? c01.y : c01.x;
            u64 whi = (prev & 64) ? c23.y : c23.x;
            u64 w   = (prev & 128) ? whi : wlo;
            unsigned int lo32 = (unsigned int)__builtin_amdgcn_readlane((int)(unsigned int)w, j);
            unsigned int hi32 = (unsigned int)__builtin_amdgcn_readlane((int)(unsigned int)(w >> 32), j);
            int c = __builtin_amdgcn_readlane(cc, j);
            u64 ww = ((u64)hi32 << 32) | (u64)lo32;
            int stick = (int)((ww >> (prev & 63)) & 1ULL);
            prev = stick ? prev : c;
            myres = (l == j) ? prev : myres;
        }
        midx[base + seg * 64 + l] = myres;
    }
}

// ---------------- fused outputs: y gather + modes one-hot ----------------
__global__ __launch_bounds__(256)
void out_k(const int* __restrict__ midx, const float* __restrict__ ytab,
           float* __restrict__ y, float* __restrict__ modes)
{
    int r = blockIdx.x, t = threadIdx.x;
    int k = midx[r];
    ((float4*)(y + (size_t)r * 1024))[t] = ((const float4*)(ytab + (size_t)k * 1024))[t];
    if (t < 64) {
        int base = t * 4;
        float4 v = make_float4(base == k ? 1.f : 0.f, base+1 == k ? 1.f : 0.f,
                               base+2 == k ? 1.f : 0.f, base+3 == k ? 1.f : 0.f);
        ((float4*)(modes + (size_t)r * 256))[t] = v;
    }
}

extern "C" void kernel_launch(void* const* d_in, const int* in_sizes, int n_in,
                              void* d_out, int out_size, void* d_ws, size_t ws_size,
                              hipStream_t stream)
{
    const float* x       = (const float*)d_in[0];
    const float* prevm   = (const float*)d_in[1];
    const float* Wtr_w   = (const float*)d_in[2];
    const float* Wtr_b   = (const float*)d_in[3];
    const float* Wms_w   = (const float*)d_in[4];
    const float* Wms_b   = (const float*)d_in[5];
    const float* Mw      = (const float*)d_in[6];
    const float* g       = (const float*)d_in[7];
    const float* Wrd_w   = (const float*)d_in[8];
    const float* Wrd_b   = (const float*)d_in[9];
    const float* bkeys   = (const float*)d_in[10];
    const float* bvals   = (const float*)d_in[11];
    const float* bused   = (const float*)d_in[12];

    float* y_out     = (float*)d_out;
    float* modes_out = y_out + (size_t)ROWS * DOUTD;

    char* w = (char*)d_ws;
    size_t o = 0;
    auto alloc = [&](size_t b) { size_t r = o; o = (o + b + 255) & ~(size_t)255; return r; };

    size_t oMask = alloc((size_t)ROWS * 32);
    size_t oCar  = alloc((size_t)ROWS * 4);
    size_t oMidx = alloc((size_t)ROWS * 4);
    size_t oFlag = alloc((size_t)ROWS * 4);
    size_t oInv  = alloc((size_t)BANKN * 4);
    size_t oPMw  = alloc((size_t)KDIM * DMDIM * 4);
    size_t oPbk  = alloc((size_t)BANKN * DMDIM * 4);
    size_t oPbvT = alloc((size_t)DMDIM * BANKN * 4);
    size_t oPWrd = alloc((size_t)DOUTD * DMDIM * 4);
    size_t oSc   = alloc((size_t)KDIM * BANKN * 4);
    size_t oPat  = alloc((size_t)KDIM * BANKN * 4);
    size_t oPB   = alloc((size_t)8 * KDIM * DMDIM * 4);
    size_t oPrn  = alloc((size_t)KDIM * DMDIM * 4);
    size_t oYtp  = alloc((size_t)4 * KDIM * DOUTD * 4);
    size_t oYt   = alloc((size_t)KDIM * DOUTD * 4);
    size_t oW1   = alloc((size_t)HDIMD * DIND * 4);
    size_t oW2   = alloc((size_t)KDIM * HDIMD * 4);
    size_t oRidx = alloc((size_t)FPAD * 4);
    size_t oCnt  = alloc(256);
    size_t oXg   = alloc((size_t)FPAD * DIND * 4);
    size_t oHg   = alloc((size_t)FPAD * HDIMD * 4);
    size_t oLgg  = alloc((size_t)FPAD * 256 * 4);
    size_t persist = o;

    // adaptive chunk: need persist + CM*4096 (px, aliased by p2) + CM*8192 (ph)
    int CM = ROWS;
    while (CM > 256 && persist + (size_t)CM * 12288 > ws_size) CM >>= 1;
    size_t oPx = alloc((size_t)CM * DIND * 4);     // also p2 (4 * CM * 256 * 4 == same size)
    size_t oPh = alloc((size_t)CM * HDIMD * 4);

    u64*   masks = (u64*)(w + oMask);
    int*   cArr  = (int*)(w + oCar);
    int*   midx  = (int*)(w + oMidx);
    int*   flags = (int*)(w + oFlag);
    float* invkn = (float*)(w + oInv);
    uint4* pMw   = (uint4*)(w + oPMw);
    uint4* pbk   = (uint4*)(w + oPbk);
    uint4* pbvT  = (uint4*)(w + oPbvT);
    uint4* pWrdT = (uint4*)(w + oPWrd);
    float* scores= (float*)(w + oSc);
    uint4* pattn = (uint4*)(w + oPat);
    float* partB = (float*)(w + oPB);
    uint4* prn   = (uint4*)(w + oPrn);
    float* ytabp = (float*)(w + oYtp);
    float* ytab  = (float*)(w + oYt);
    uint4* pWtrT = (uint4*)(w + oW1);
    uint4* pWmsT = (uint4*)(w + oW2);
    int*   ridx  = (int*)(w + oRidx);
    int*   cnt   = (int*)(w + oCnt);
    float* xg    = (float*)(w + oXg);
    float* hg    = (float*)(w + oHg);
    float* lgg   = (float*)(w + oLgg);
    uint4* px    = (uint4*)(w + oPx);
    float* p2    = (float*)(w + oPx);   // alias: px dead once GEMM1 of the chunk is done
    uint4* ph    = (uint4*)(w + oPh);

    // ---- pack params (once) ----
    packrows_k<<<1024, 256, 0, stream>>>(bkeys, pbk, (long)BANKN * DMDIM / 8);
    packrows_k<<<64, 256, 0, stream>>>(Mw, pMw, (long)KDIM * DMDIM / 8);
    tsplit_k<<<dim3(HDIMD/32, DIND/32), 256, 0, stream>>>(Wtr_w, pWtrT, DIND, HDIMD);
    tsplit_k<<<dim3(KDIM/32, HDIMD/32), 256, 0, stream>>>(Wms_w, pWmsT, HDIMD, KDIM);
    tsplit_k<<<dim3(DMDIM/32, BANKN/32), 256, 0, stream>>>(bvals, pbvT, BANKN, DMDIM);
    tsplit_k<<<dim3(DOUTD/32, DMDIM/32), 256, 0, stream>>>(Wrd_w, pWrdT, DMDIM, DOUTD);
    invkn_k<<<BANKN, 64, 0, stream>>>(bkeys, invkn);

    // ---- table pipeline (all MFMA) ----
    gemm_mfma<0><<<dim3(32, 2, 1), 256, 0, stream>>>(pMw, pbk, nullptr, scores, DMDIM, DMDIM);
    softmax_k<<<KDIM, 256, 0, stream>>>(Mw, invkn, bused, scores, pattn);
    gemm_mfma<0><<<dim3(4, 2, 8), 256, 0, stream>>>(pattn, pbvT, nullptr, partB, BANKN, BANKN/8);
    redk_rn_k<<<KDIM, 64, 0, stream>>>(partB, Mw, g, prn);
    gemm_mfma<0><<<dim3(8, 2, 4), 256, 0, stream>>>(prn, pWrdT, nullptr, ytabp, DMDIM, DMDIM/4);
    ytabred_k<<<KDIM, 256, 0, stream>>>(ytabp, Wrd_b, ytab);

    // ---- front GEMMs (chunked; GEMM1 writes octet-planar h directly) ----
    for (int ch0 = 0; ch0 < ROWS; ch0 += CM) {
        packrows_k<<<CM / 2, 256, 0, stream>>>(x + (size_t)ch0 * DIND, px, (long)CM * 128);
        gemm_mfma<1><<<dim3(HDIMD/128, CM/128, 1), 256, 0, stream>>>(px, pWtrT, Wtr_b, ph, DIND, DIND);
        gemm_mfma<0><<<dim3(KDIM/128, CM/128, 4), 256, 0, stream>>>(ph, pWmsT, nullptr, p2, HDIMD, HDIMD/4);
        logits_flag_k<<<CM, 64, 0, stream>>>(p2, Wms_b, masks + (size_t)ch0 * 4,
                                             cArr + ch0, flags + ch0, CM);
    }

    // ---- fixup risky rows in exact fp32 ----
    hipMemsetAsync(cnt, 0, 4, stream);
    compact_k<<<ROWS/256, 256, 0, stream>>>(flags, ridx, cnt);
    gatherx_k<<<FPAD, 256, 0, stream>>>(x, ridx, cnt, xg);
    gemm64<true><<<dim3(HDIMD/64, FPAD/64), 256, 0, stream>>>(xg, Wtr_w, Wtr_b, hg, HDIMD, DIND, cnt);
    gemm64<false><<<dim3(256/64, FPAD/64), 256, 0, stream>>>(hg, Wms_w, Wms_b, lgg, 256, HDIMD, cnt);
    fixmask_k<<<FPAD, 64, 0, stream>>>(lgg, ridx, cnt, masks, cArr);

    // ---- scan + outputs ----
    scan2_k<<<8, 64, 0, stream>>>(masks, cArr, prevm, midx);
    out_k<<<ROWS, 256, 0, stream>>>(midx, ytab, y_out, modes_out);
}